// Round 9
// baseline (460.957 us; speedup 1.0000x reference)
//
#include <hip/hip_runtime.h>
#include <hip/hip_bf16.h>

#define NNODES 100000
#define NEDGES 1600000
#define KDIM 256
#define ODIM 128
#define NXCD 8            // counts replicated per-XCD; selected by HW_REG_XCC_ID
#define NB_SCAN 391       // ceil(100000 / 256)
#define EDGE_CAP 1900032  // 1.6M + 3*100000, rounded up a bit
#define GEMM_BLOCKS 1563  // ceil(100000 / 64)
#define EDGE_BLOCKS 1563  // ceil(400000 / 256); thread i owns edges [4i, 4i+4)
#define CONV_BLOCKS 128   // ceil(32768 / 256)

typedef __attribute__((ext_vector_type(8))) short short8;
typedef __attribute__((ext_vector_type(4))) float floatx4;

// round-to-nearest-even f32 -> bf16 (inputs are finite Gaussians; no NaN handling needed)
static __device__ __forceinline__ short f2bf(float f) {
  union { float f; unsigned u; } x; x.f = f;
  unsigned r = (x.u + 0x7fffu + ((x.u >> 16) & 1u)) >> 16;
  return (short)r;
}

// K1: conv_w (128 blocks) || histogram (1563 blocks).
// Histogram: per-XCD counts copy (8 x 400 KB, each L2-resident), XCD-local
// workgroup-scope relaxed atomics with the RESULT DISCARDED -> compiler emits
// non-returning global_atomic_add: waves fire-and-forget, no 600-cycle return
// stalls. No rank buffer exists anymore (slot assignment moved to place's
// returning cursor atomic).
__global__ __launch_bounds__(256) void conv_hist_kernel(
    const float* __restrict__ W, short* __restrict__ Wb,
    const int* __restrict__ rows, unsigned* __restrict__ counts) {
  if (blockIdx.x < CONV_BLOCKS) {
    int i = blockIdx.x * 256 + threadIdx.x;
    if (i < ODIM * KDIM) Wb[i] = f2bf(W[i]);
    return;
  }
  unsigned xcc;
  asm("s_getreg_b32 %0, hwreg(HW_REG_XCC_ID)" : "=s"(xcc));
  xcc &= 7u;
  unsigned* cbase = counts + (size_t)xcc * NNODES;
  const int e0 = ((blockIdx.x - CONV_BLOCKS) * 256 + threadIdx.x) * 4;
  if (e0 < NEDGES) {
    const int4 r4 = *(const int4*)(rows + e0);
    __hip_atomic_fetch_add(&cbase[r4.x], 1u, __ATOMIC_RELAXED, __HIP_MEMORY_SCOPE_WORKGROUP);
    __hip_atomic_fetch_add(&cbase[r4.y], 1u, __ATOMIC_RELAXED, __HIP_MEMORY_SCOPE_WORKGROUP);
    __hip_atomic_fetch_add(&cbase[r4.z], 1u, __ATOMIC_RELAXED, __HIP_MEMORY_SCOPE_WORKGROUP);
    __hip_atomic_fetch_add(&cbase[r4.w], 1u, __ATOMIC_RELAXED, __HIP_MEMORY_SCOPE_WORKGROUP);
  }
}

// K2: scan1. Per node sum the 8 per-XCD counts, pad to multiple of 4 (spmm
// reads int4 pairs), block-level exclusive scan -> chunkExcl + blockSums.
__global__ __launch_bounds__(256) void scan1_kernel(
    const unsigned* __restrict__ counts, int* __restrict__ chunkExcl,
    int* __restrict__ blockSums) {
  __shared__ int s[256];
  int t = threadIdx.x;
  int n = blockIdx.x * 256 + t;
  int sum = 0;
  if (n < NNODES) {
    int s0 = 0;
#pragma unroll
    for (int x = 0; x < NXCD; x++) s0 += (int)counts[(size_t)x * NNODES + n];
    sum = (s0 + 3) & ~3;  // pad segment to multiple of 4 records
  }
  s[t] = sum;
  __syncthreads();
  for (int o = 1; o < 256; o <<= 1) {
    int add = (t >= o) ? s[t - o] : 0;
    __syncthreads();
    s[t] += add;
    __syncthreads();
  }
  if (n < NNODES) chunkExcl[n] = s[t] - sum;
  if (t == 255) blockSums[blockIdx.x] = s[255];
}

// K3: merged scan2+scan3+pad-write. 391 blocks x 512 threads. Each block
// redundantly scans the 391 blockSums in LDS to get its base (kills the serial
// scan2 dispatch). Per node: write offsets[n], convert the 8 per-XCD counts in
// place into absolute CURSOR positions (place's returning atomics consume and
// advance them), and zero the <=3 pad records (replaces the edges memset;
// place covers [run, run+deg), pads cover the rest).
__global__ __launch_bounds__(512) void scan23_kernel(
    const int* __restrict__ blockSums, const int* __restrict__ chunkExcl,
    unsigned* __restrict__ counts, int* __restrict__ offsets,
    int2* __restrict__ edges) {
  __shared__ int s[512];
  const int t = threadIdx.x;
  s[t] = (t < NB_SCAN) ? blockSums[t] : 0;
  __syncthreads();
  for (int o = 1; o < 512; o <<= 1) {
    int add = (t >= o) ? s[t - o] : 0;
    __syncthreads();
    s[t] += add;
    __syncthreads();
  }
  // s[] now holds the inclusive scan of blockSums
  const int myBase = (blockIdx.x == 0) ? 0 : s[blockIdx.x - 1];
  if (blockIdx.x == 0 && t == 0) offsets[NNODES] = s[NB_SCAN - 1];
  if (t < 256) {
    const int n = blockIdx.x * 256 + t;
    if (n < NNODES) {
      const int run = chunkExcl[n] + myBase;   // multiple of 4
      offsets[n] = run;
      int c[NXCD];
      int deg = 0;
#pragma unroll
      for (int x = 0; x < NXCD; x++) {
        c[x] = (int)counts[(size_t)x * NNODES + n];
        deg += c[x];
      }
      int acc2 = run;
#pragma unroll
      for (int x = 0; x < NXCD; x++) {
        counts[(size_t)x * NNODES + n] = (unsigned)acc2;
        acc2 += c[x];
      }
      const int padded = (deg + 3) & ~3;
      const int2 zrec = {0, 0};
      for (int p = run + deg; p < run + padded; p++) edges[p] = zrec;  // pad = {col 0, val 0}
    }
  }
}

// K4: place (first 1563 blocks) || gemm (next 1563 blocks) — place's
// atomic-return + scattered-store latency hides under gemm's MFMA+streaming
// (same mechanism that hid scan1 under gemm in round 8: 88 us ≈ gemm alone).
//
// place: slot = returning XCD-local atomic on the cursor (the scan output).
// Slots within [base_x[r], base_x[r]+c_x[r]) are unique; edge order within a
// segment is arbitrary (sum is commutative; tolerance covers rounding).
//
// gemm: round-3 structure (measured 90 us): 64 rows/block, 16 rows/wave, all
// 8 n-tiles per wave; K-loop fully unrolled, 2-deep register double-buffer.
// D layout: col = t*16 + (lane&15), row = quad*4 + reg  [m89 layout]
// H stored PACKED: u32 word j = (bf16 col j) | (bf16 col j+64)<<16.
__global__ __launch_bounds__(256) void gemm_place_kernel(
    const float* __restrict__ X, const short* __restrict__ Wb,
    const float* __restrict__ bias, unsigned* __restrict__ H2,
    const int* __restrict__ rows, const int* __restrict__ cols,
    const float* __restrict__ vals, unsigned* __restrict__ cursor,
    int2* __restrict__ edges) {
  if (blockIdx.x < EDGE_BLOCKS) {
    unsigned xcc;
    asm("s_getreg_b32 %0, hwreg(HW_REG_XCC_ID)" : "=s"(xcc));
    xcc &= 7u;
    unsigned* cur = cursor + (size_t)xcc * NNODES;
    const int e0 = (blockIdx.x * 256 + threadIdx.x) * 4;
    if (e0 < NEDGES) {
      const int4 r4 = *(const int4*)(rows + e0);
      const int4 c4 = *(const int4*)(cols + e0);
      const float4 v4 = *(const float4*)(vals + e0);
      int2 rec;
      unsigned p;
      p = __hip_atomic_fetch_add(&cur[r4.x], 1u, __ATOMIC_RELAXED, __HIP_MEMORY_SCOPE_WORKGROUP);
      rec.x = c4.x; rec.y = __float_as_int(v4.x); edges[p] = rec;
      p = __hip_atomic_fetch_add(&cur[r4.y], 1u, __ATOMIC_RELAXED, __HIP_MEMORY_SCOPE_WORKGROUP);
      rec.x = c4.y; rec.y = __float_as_int(v4.y); edges[p] = rec;
      p = __hip_atomic_fetch_add(&cur[r4.z], 1u, __ATOMIC_RELAXED, __HIP_MEMORY_SCOPE_WORKGROUP);
      rec.x = c4.z; rec.y = __float_as_int(v4.z); edges[p] = rec;
      p = __hip_atomic_fetch_add(&cur[r4.w], 1u, __ATOMIC_RELAXED, __HIP_MEMORY_SCOPE_WORKGROUP);
      rec.x = c4.w; rec.y = __float_as_int(v4.w); edges[p] = rec;
    }
    return;
  }
  // ---- gemm path ----
  const int gb = blockIdx.x - EDGE_BLOCKS;
  const int lane = threadIdx.x & 63;
  const int wave = threadIdx.x >> 6;
  const int l16 = lane & 15;
  const int quad = lane >> 4;
  const int rowBase = gb * 64 + wave * 16;
  const int arow = rowBase + l16;
  const bool inb = arow < NNODES;
  const float4 zf4 = {0.f, 0.f, 0.f, 0.f};
  const float4* xp = (const float4*)(X + (size_t)(inb ? arow : 0) * KDIM + quad * 8);

  floatx4 acc[8];
#pragma unroll
  for (int t = 0; t < 8; t++) acc[t] = (floatx4){0.f, 0.f, 0.f, 0.f};

  float4 c0 = inb ? xp[0] : zf4;
  float4 c1 = inb ? xp[1] : zf4;
#pragma unroll
  for (int k0 = 0; k0 < 8; k0++) {
    float4 n0, n1;
    if (k0 < 7) {
      n0 = inb ? xp[(k0 + 1) * 8] : zf4;
      n1 = inb ? xp[(k0 + 1) * 8 + 1] : zf4;
    }
    short8 a;
    a[0] = f2bf(c0.x); a[1] = f2bf(c0.y); a[2] = f2bf(c0.z); a[3] = f2bf(c0.w);
    a[4] = f2bf(c1.x); a[5] = f2bf(c1.y); a[6] = f2bf(c1.z); a[7] = f2bf(c1.w);
    const short* bp = Wb + k0 * 32 + quad * 8;
#pragma unroll
    for (int t = 0; t < 8; t++) {
      short8 b = *(const short8*)(bp + (size_t)(t * 16 + l16) * KDIM);
      acc[t] = __builtin_amdgcn_mfma_f32_16x16x32_bf16(a, b, acc[t], 0, 0, 0);
    }
    if (k0 < 7) { c0 = n0; c1 = n1; }
  }

#pragma unroll
  for (int t = 0; t < 4; t++) {
    const int cl = t * 16 + l16;
    const float blo = bias[cl];
    const float bhi = bias[cl + 64];
#pragma unroll
    for (int r = 0; r < 4; r++) {
      const int row = rowBase + quad * 4 + r;
      if (row < NNODES) {
        unsigned lo = (unsigned short)f2bf(acc[t][r] + blo);
        unsigned hi = (unsigned short)f2bf(acc[t + 4][r] + bhi);
        H2[(size_t)row * 64 + cl] = lo | (hi << 16);
      }
    }
  }
}

// K5: one wave per output row. Lane owns channels {lane, lane+64} (one uint =
// packed bf16 pair per gathered H row -> 256 B coalesced per edge). Segments
// padded to multiple of 4 records (pads are {col 0, val 0}) -> no tail loop.
__global__ __launch_bounds__(256) void spmm_kernel(const int* __restrict__ offsets,
                                                   const int2* __restrict__ edges,
                                                   const unsigned* __restrict__ H2,
                                                   float* __restrict__ out) {
  const int lane = threadIdx.x & 63;
  const int row = blockIdx.x * 4 + (threadIdx.x >> 6);
  if (row >= NNODES) return;
  const int s = offsets[row];      // multiple of 4
  const int e = offsets[row + 1];
  float ax = 0.f, ay = 0.f;
  for (int i = s; i < e; i += 4) {
    const int4 p01 = *(const int4*)(edges + i);      // 16 B aligned (s % 4 == 0)
    const int4 p23 = *(const int4*)(edges + i + 2);
    const unsigned h0 = H2[(size_t)p01.x * 64 + lane];
    const unsigned h1 = H2[(size_t)p01.z * 64 + lane];
    const unsigned h2 = H2[(size_t)p23.x * 64 + lane];
    const unsigned h3 = H2[(size_t)p23.z * 64 + lane];
    const float v0 = __int_as_float(p01.y);
    const float v1 = __int_as_float(p01.w);
    const float v2 = __int_as_float(p23.y);
    const float v3 = __int_as_float(p23.w);
    ax += v0 * __uint_as_float(h0 << 16);            // col = lane
    ay += v0 * __uint_as_float(h0 & 0xffff0000u);    // col = lane + 64
    ax += v1 * __uint_as_float(h1 << 16);
    ay += v1 * __uint_as_float(h1 & 0xffff0000u);
    ax += v2 * __uint_as_float(h2 << 16);
    ay += v2 * __uint_as_float(h2 & 0xffff0000u);
    ax += v3 * __uint_as_float(h3 << 16);
    ay += v3 * __uint_as_float(h3 & 0xffff0000u);
  }
  out[(size_t)row * 128 + lane] = ax;
  out[(size_t)row * 128 + 64 + lane] = ay;
}

extern "C" void kernel_launch(void* const* d_in, const int* in_sizes, int n_in,
                              void* d_out, int out_size, void* d_ws, size_t ws_size,
                              hipStream_t stream) {
  const float* X = (const float*)d_in[0];
  const int* erow = (const int*)d_in[1];
  const int* ecol = (const int*)d_in[2];
  const float* eval = (const float*)d_in[3];
  const float* W = (const float*)d_in[4];
  const float* bias = (const float*)d_in[5];
  float* out = (float*)d_out;

  char* ws = (char*)d_ws;
  size_t off = 0;
  auto alloc = [&](size_t bytes) -> char* {
    char* p = ws + off;
    off += (bytes + 255) & ~(size_t)255;
    return p;
  };
  unsigned* Hb = (unsigned*)alloc((size_t)NNODES * 64 * 4);       // 25.6 MB packed
  short* Wb = (short*)alloc((size_t)ODIM * KDIM * 2);             // 64 KB
  unsigned* counts = (unsigned*)alloc((size_t)NXCD * NNODES * 4); // 3.2 MB (-> cursors)
  int* chunkExcl = (int*)alloc((size_t)NNODES * 4);
  int* offsets = (int*)alloc((size_t)(NNODES + 1) * 4);
  int* blockSums = (int*)alloc((size_t)NB_SCAN * 4);
  int2* edges = (int2*)alloc((size_t)EDGE_CAP * 8);  // 15.2 MB, padded CSR records

  hipMemsetAsync(counts, 0, (size_t)NXCD * NNODES * 4, stream);
  conv_hist_kernel<<<CONV_BLOCKS + EDGE_BLOCKS, 256, 0, stream>>>(W, Wb, erow, counts);
  scan1_kernel<<<NB_SCAN, 256, 0, stream>>>(counts, chunkExcl, blockSums);
  scan23_kernel<<<NB_SCAN, 512, 0, stream>>>(blockSums, chunkExcl, counts, offsets, edges);
  gemm_place_kernel<<<EDGE_BLOCKS + GEMM_BLOCKS, 256, 0, stream>>>(
      X, Wb, bias, Hb, erow, ecol, eval, counts, edges);
  spmm_kernel<<<(NNODES + 3) / 4, 256, 0, stream>>>(offsets, edges, (const unsigned*)Hb, out);
}

// Round 10
// 378.833 us; speedup vs baseline: 1.2168x; 1.2168x over previous
//
#include <hip/hip_runtime.h>
#include <hip/hip_bf16.h>

#define NNODES 100000
#define NEDGES 1600000
#define KDIM 256
#define ODIM 128
#define NXCD 8            // counts replicated per-XCD; selected by HW_REG_XCC_ID
#define NB_SCAN 391       // ceil(100000 / 256)
#define EDGE_CAP 1900032  // 1.6M + 3*100000, rounded up a bit
#define GEMM_BLOCKS 1563  // ceil(100000 / 64)
#define EDGE_BLOCKS 1563  // ceil(400000 / 256); thread i owns edges [4i, 4i+4)
#define CONV_BLOCKS 128   // ceil(32768 / 256)
#define ZERO_BLOCKS 3125  // 8*100000 uints / 256

typedef __attribute__((ext_vector_type(8))) short short8;
typedef __attribute__((ext_vector_type(4))) float floatx4;

// round-to-nearest-even f32 -> bf16 (inputs are finite Gaussians; no NaN handling needed)
static __device__ __forceinline__ short f2bf(float f) {
  union { float f; unsigned u; } x; x.f = f;
  unsigned r = (x.u + 0x7fffu + ((x.u >> 16) & 1u)) >> 16;
  return (short)r;
}

// K0: init — conv_w (128 blocks) + zero the 8 per-XCD counts copies (3125
// blocks). Replaces hipMemsetAsync + the separate conv_w dispatch.
__global__ __launch_bounds__(256) void init_kernel(
    const float* __restrict__ W, short* __restrict__ Wb,
    unsigned* __restrict__ counts) {
  if (blockIdx.x < CONV_BLOCKS) {
    int i = blockIdx.x * 256 + threadIdx.x;
    if (i < ODIM * KDIM) Wb[i] = f2bf(W[i]);
    return;
  }
  int i = (blockIdx.x - CONV_BLOCKS) * 256 + threadIdx.x;
  if (i < NXCD * NNODES) counts[i] = 0u;
}

// K1: gemm (blocks [0, GEMM_BLOCKS)) || rank (blocks after) — the round-0
// topology (measured 126 us fused vs 88 gemm-alone; rank rides along nearly
// free), with XCD-local atomics: each XCD increments its own 400 KB counts
// copy (L2-resident), rank stores (xcc<<8)|local_rank so the later place pass
// needs NO atomics and NO block->XCD mapping assumption.
//
// gemm: 64 rows/block, 16 rows/wave, all 8 n-tiles per wave; K-loop fully
// unrolled, 2-deep register double-buffer on the X loads.
// D layout: col = t*16 + (lane&15), row = quad*4 + reg  [m89 layout]
// H stored PACKED: u32 word j = (bf16 col j) | (bf16 col j+64)<<16.
__global__ __launch_bounds__(256) void gemm_rank_kernel(
    const float* __restrict__ X, const short* __restrict__ Wb,
    const float* __restrict__ bias, unsigned* __restrict__ H2,
    const int* __restrict__ rows, unsigned* __restrict__ counts,
    unsigned short* __restrict__ rank) {
  if (blockIdx.x >= GEMM_BLOCKS) {
    // ---- rank path: exact partition, thread owns edges [4i, 4i+4) ----
    unsigned xcc;
    asm("s_getreg_b32 %0, hwreg(HW_REG_XCC_ID)" : "=s"(xcc));
    xcc &= 7u;
    unsigned* cbase = counts + (size_t)xcc * NNODES;
    const int e0 = ((blockIdx.x - GEMM_BLOCKS) * 256 + threadIdx.x) * 4;
    if (e0 < NEDGES) {
      const int4 r4 = *(const int4*)(rows + e0);
      const unsigned o0 = __hip_atomic_fetch_add(&cbase[r4.x], 1u, __ATOMIC_RELAXED,
                                                 __HIP_MEMORY_SCOPE_WORKGROUP);
      const unsigned o1 = __hip_atomic_fetch_add(&cbase[r4.y], 1u, __ATOMIC_RELAXED,
                                                 __HIP_MEMORY_SCOPE_WORKGROUP);
      const unsigned o2 = __hip_atomic_fetch_add(&cbase[r4.z], 1u, __ATOMIC_RELAXED,
                                                 __HIP_MEMORY_SCOPE_WORKGROUP);
      const unsigned o3 = __hip_atomic_fetch_add(&cbase[r4.w], 1u, __ATOMIC_RELAXED,
                                                 __HIP_MEMORY_SCOPE_WORKGROUP);
      ushort4 rk;
      rk.x = (unsigned short)((xcc << 8) | o0);
      rk.y = (unsigned short)((xcc << 8) | o1);
      rk.z = (unsigned short)((xcc << 8) | o2);
      rk.w = (unsigned short)((xcc << 8) | o3);
      *(ushort4*)(rank + e0) = rk;   // 8 B aligned (e0 % 4 == 0)
    }
    return;
  }
  // ---- gemm path ----
  const int lane = threadIdx.x & 63;
  const int wave = threadIdx.x >> 6;
  const int l16 = lane & 15;
  const int quad = lane >> 4;
  const int rowBase = blockIdx.x * 64 + wave * 16;
  const int arow = rowBase + l16;
  const bool inb = arow < NNODES;
  const float4 zf4 = {0.f, 0.f, 0.f, 0.f};
  const float4* xp = (const float4*)(X + (size_t)(inb ? arow : 0) * KDIM + quad * 8);

  floatx4 acc[8];
#pragma unroll
  for (int t = 0; t < 8; t++) acc[t] = (floatx4){0.f, 0.f, 0.f, 0.f};

  float4 c0 = inb ? xp[0] : zf4;
  float4 c1 = inb ? xp[1] : zf4;
#pragma unroll
  for (int k0 = 0; k0 < 8; k0++) {
    float4 n0, n1;
    if (k0 < 7) {
      n0 = inb ? xp[(k0 + 1) * 8] : zf4;
      n1 = inb ? xp[(k0 + 1) * 8 + 1] : zf4;
    }
    short8 a;
    a[0] = f2bf(c0.x); a[1] = f2bf(c0.y); a[2] = f2bf(c0.z); a[3] = f2bf(c0.w);
    a[4] = f2bf(c1.x); a[5] = f2bf(c1.y); a[6] = f2bf(c1.z); a[7] = f2bf(c1.w);
    const short* bp = Wb + k0 * 32 + quad * 8;
#pragma unroll
    for (int t = 0; t < 8; t++) {
      short8 b = *(const short8*)(bp + (size_t)(t * 16 + l16) * KDIM);
      acc[t] = __builtin_amdgcn_mfma_f32_16x16x32_bf16(a, b, acc[t], 0, 0, 0);
    }
    if (k0 < 7) { c0 = n0; c1 = n1; }
  }

#pragma unroll
  for (int t = 0; t < 4; t++) {
    const int cl = t * 16 + l16;
    const float blo = bias[cl];
    const float bhi = bias[cl + 64];
#pragma unroll
    for (int r = 0; r < 4; r++) {
      const int row = rowBase + quad * 4 + r;
      if (row < NNODES) {
        unsigned lo = (unsigned short)f2bf(acc[t][r] + blo);
        unsigned hi = (unsigned short)f2bf(acc[t + 4][r] + bhi);
        H2[(size_t)row * 64 + cl] = lo | (hi << 16);
      }
    }
  }
}

// K2: scan1. Per node sum the 8 per-XCD counts, pad to multiple of 4 (spmm
// reads int4 pairs), block-level exclusive scan -> chunkExcl + blockSums.
__global__ __launch_bounds__(256) void scan1_kernel(
    const unsigned* __restrict__ counts, int* __restrict__ chunkExcl,
    int* __restrict__ blockSums) {
  __shared__ int s[256];
  int t = threadIdx.x;
  int n = blockIdx.x * 256 + t;
  int sum = 0;
  if (n < NNODES) {
    int s0 = 0;
#pragma unroll
    for (int x = 0; x < NXCD; x++) s0 += (int)counts[(size_t)x * NNODES + n];
    sum = (s0 + 3) & ~3;  // pad segment to multiple of 4 records
  }
  s[t] = sum;
  __syncthreads();
  for (int o = 1; o < 256; o <<= 1) {
    int add = (t >= o) ? s[t - o] : 0;
    __syncthreads();
    s[t] += add;
    __syncthreads();
  }
  if (n < NNODES) chunkExcl[n] = s[t] - sum;
  if (t == 255) blockSums[blockIdx.x] = s[255];
}

// K3: merged scan2+scan3+pad-write. 391 blocks x 512 threads. Each block
// redundantly scans the 391 blockSums in LDS to get its base (kills the serial
// scan2 dispatch). Per node: write offsets[n], convert the 8 per-XCD counts in
// place into absolute per-XCD base positions, and zero the <=3 pad records
// (replaces the edges memset; place covers [run, run+deg), pads the rest).
__global__ __launch_bounds__(512) void scan23_kernel(
    const int* __restrict__ blockSums, const int* __restrict__ chunkExcl,
    unsigned* __restrict__ counts, int* __restrict__ offsets,
    int2* __restrict__ edges) {
  __shared__ int s[512];
  const int t = threadIdx.x;
  s[t] = (t < NB_SCAN) ? blockSums[t] : 0;
  __syncthreads();
  for (int o = 1; o < 512; o <<= 1) {
    int add = (t >= o) ? s[t - o] : 0;
    __syncthreads();
    s[t] += add;
    __syncthreads();
  }
  // s[] now holds the inclusive scan of blockSums
  const int myBase = (blockIdx.x == 0) ? 0 : s[blockIdx.x - 1];
  if (blockIdx.x == 0 && t == 0) offsets[NNODES] = s[NB_SCAN - 1];
  if (t < 256) {
    const int n = blockIdx.x * 256 + t;
    if (n < NNODES) {
      const int run = chunkExcl[n] + myBase;   // multiple of 4
      offsets[n] = run;
      int c[NXCD];
      int deg = 0;
#pragma unroll
      for (int x = 0; x < NXCD; x++) {
        c[x] = (int)counts[(size_t)x * NNODES + n];
        deg += c[x];
      }
      int acc2 = run;
#pragma unroll
      for (int x = 0; x < NXCD; x++) {
        counts[(size_t)x * NNODES + n] = (unsigned)acc2;
        acc2 += c[x];
      }
      const int padded = (deg + 3) & ~3;
      const int2 zrec = {0, 0};
      for (int p = run + deg; p < run + padded; p++) edges[p] = zrec;  // pad = {col 0, val 0}
    }
  }
}

// K4: atomic-free placement: pos = xcdBase[xcc_at_rank_time][row] + local_rank.
// Exact 4-contiguous partition, vectorized int4/float4/ushort4 loads. No
// dependence on this dispatch's block->XCD mapping (xcc is carried in rank).
__global__ __launch_bounds__(256) void place_kernel(
    const int* __restrict__ rows, const int* __restrict__ cols,
    const float* __restrict__ vals, const unsigned short* __restrict__ rank,
    const unsigned* __restrict__ sbase, int2* __restrict__ edges) {
  const int e0 = (blockIdx.x * 256 + threadIdx.x) * 4;
  if (e0 < NEDGES) {
    const int4 r4 = *(const int4*)(rows + e0);
    const int4 c4 = *(const int4*)(cols + e0);
    const float4 v4 = *(const float4*)(vals + e0);
    const ushort4 k4 = *(const ushort4*)(rank + e0);
    int2 rec;
    rec.x = c4.x; rec.y = __float_as_int(v4.x);
    edges[(int)sbase[(size_t)(k4.x >> 8) * NNODES + r4.x] + (int)(k4.x & 255u)] = rec;
    rec.x = c4.y; rec.y = __float_as_int(v4.y);
    edges[(int)sbase[(size_t)(k4.y >> 8) * NNODES + r4.y] + (int)(k4.y & 255u)] = rec;
    rec.x = c4.z; rec.y = __float_as_int(v4.z);
    edges[(int)sbase[(size_t)(k4.z >> 8) * NNODES + r4.z] + (int)(k4.z & 255u)] = rec;
    rec.x = c4.w; rec.y = __float_as_int(v4.w);
    edges[(int)sbase[(size_t)(k4.w >> 8) * NNODES + r4.w] + (int)(k4.w & 255u)] = rec;
  }
}

// K5: one wave per output row. Lane owns channels {lane, lane+64} (one uint =
// packed bf16 pair per gathered H row -> 256 B coalesced per edge). Segments
// padded to multiple of 4 records (pads are {col 0, val 0}) -> no tail loop.
__global__ __launch_bounds__(256) void spmm_kernel(const int* __restrict__ offsets,
                                                   const int2* __restrict__ edges,
                                                   const unsigned* __restrict__ H2,
                                                   float* __restrict__ out) {
  const int lane = threadIdx.x & 63;
  const int row = blockIdx.x * 4 + (threadIdx.x >> 6);
  if (row >= NNODES) return;
  const int s = offsets[row];      // multiple of 4
  const int e = offsets[row + 1];
  float ax = 0.f, ay = 0.f;
  for (int i = s; i < e; i += 4) {
    const int4 p01 = *(const int4*)(edges + i);      // 16 B aligned (s % 4 == 0)
    const int4 p23 = *(const int4*)(edges + i + 2);
    const unsigned h0 = H2[(size_t)p01.x * 64 + lane];
    const unsigned h1 = H2[(size_t)p01.z * 64 + lane];
    const unsigned h2 = H2[(size_t)p23.x * 64 + lane];
    const unsigned h3 = H2[(size_t)p23.z * 64 + lane];
    const float v0 = __int_as_float(p01.y);
    const float v1 = __int_as_float(p01.w);
    const float v2 = __int_as_float(p23.y);
    const float v3 = __int_as_float(p23.w);
    ax += v0 * __uint_as_float(h0 << 16);            // col = lane
    ay += v0 * __uint_as_float(h0 & 0xffff0000u);    // col = lane + 64
    ax += v1 * __uint_as_float(h1 << 16);
    ay += v1 * __uint_as_float(h1 & 0xffff0000u);
    ax += v2 * __uint_as_float(h2 << 16);
    ay += v2 * __uint_as_float(h2 & 0xffff0000u);
    ax += v3 * __uint_as_float(h3 << 16);
    ay += v3 * __uint_as_float(h3 & 0xffff0000u);
  }
  out[(size_t)row * 128 + lane] = ax;
  out[(size_t)row * 128 + 64 + lane] = ay;
}

extern "C" void kernel_launch(void* const* d_in, const int* in_sizes, int n_in,
                              void* d_out, int out_size, void* d_ws, size_t ws_size,
                              hipStream_t stream) {
  const float* X = (const float*)d_in[0];
  const int* erow = (const int*)d_in[1];
  const int* ecol = (const int*)d_in[2];
  const float* eval = (const float*)d_in[3];
  const float* W = (const float*)d_in[4];
  const float* bias = (const float*)d_in[5];
  float* out = (float*)d_out;

  char* ws = (char*)d_ws;
  size_t off = 0;
  auto alloc = [&](size_t bytes) -> char* {
    char* p = ws + off;
    off += (bytes + 255) & ~(size_t)255;
    return p;
  };
  unsigned* Hb = (unsigned*)alloc((size_t)NNODES * 64 * 4);       // 25.6 MB packed
  short* Wb = (short*)alloc((size_t)ODIM * KDIM * 2);             // 64 KB
  unsigned* counts = (unsigned*)alloc((size_t)NXCD * NNODES * 4); // 3.2 MB (-> bases)
  int* chunkExcl = (int*)alloc((size_t)NNODES * 4);
  int* offsets = (int*)alloc((size_t)(NNODES + 1) * 4);
  int* blockSums = (int*)alloc((size_t)NB_SCAN * 4);
  unsigned short* rank = (unsigned short*)alloc((size_t)NEDGES * 2);  // 3.2 MB
  int2* edges = (int2*)alloc((size_t)EDGE_CAP * 8);  // 15.2 MB, padded CSR records

  init_kernel<<<CONV_BLOCKS + ZERO_BLOCKS, 256, 0, stream>>>(W, Wb, counts);
  gemm_rank_kernel<<<GEMM_BLOCKS + EDGE_BLOCKS, 256, 0, stream>>>(X, Wb, bias, Hb,
                                                                  erow, counts, rank);
  scan1_kernel<<<NB_SCAN, 256, 0, stream>>>(counts, chunkExcl, blockSums);
  scan23_kernel<<<NB_SCAN, 512, 0, stream>>>(blockSums, chunkExcl, counts, offsets, edges);
  place_kernel<<<EDGE_BLOCKS, 256, 0, stream>>>(erow, ecol, eval, rank, counts, edges);
  spmm_kernel<<<(NNODES + 3) / 4, 256, 0, stream>>>(offsets, edges, (const unsigned*)Hb, out);
}

// Round 11
// 371.165 us; speedup vs baseline: 1.2419x; 1.0207x over previous
//
#include <hip/hip_runtime.h>
#include <hip/hip_bf16.h>

#define NNODES 100000
#define NEDGES 1600000
#define KDIM 256
#define ODIM 128
#define NXCD 8            // counts replicated per-XCD; selected by HW_REG_XCC_ID
#define NB_SCAN 391       // ceil(100000 / 256)
#define EDGE_CAP 1900032  // 1.6M + 3*100000, rounded up a bit
#define GEMM_BLOCKS 1563  // ceil(100000 / 64)
#define EDGE_BLOCKS 1563  // ceil(400000 / 256); thread i owns edges [4i, 4i+4)
#define CONV_BLOCKS 128   // ceil(32768 / 256)
#define ZERO_BLOCKS 3125  // 8*100000 uints / 256

typedef __attribute__((ext_vector_type(8))) short short8;
typedef __attribute__((ext_vector_type(4))) float floatx4;

// round-to-nearest-even f32 -> bf16 (inputs are finite Gaussians; no NaN handling needed)
static __device__ __forceinline__ short f2bf(float f) {
  union { float f; unsigned u; } x; x.f = f;
  unsigned r = (x.u + 0x7fffu + ((x.u >> 16) & 1u)) >> 16;
  return (short)r;
}

// K0: init — conv_w (128 blocks) + zero the 8 per-XCD counts copies.
__global__ __launch_bounds__(256) void init_kernel(
    const float* __restrict__ W, short* __restrict__ Wb,
    unsigned* __restrict__ counts) {
  if (blockIdx.x < CONV_BLOCKS) {
    int i = blockIdx.x * 256 + threadIdx.x;
    if (i < ODIM * KDIM) Wb[i] = f2bf(W[i]);
    return;
  }
  int i = (blockIdx.x - CONV_BLOCKS) * 256 + threadIdx.x;
  if (i < NXCD * NNODES) counts[i] = 0u;
}

// K1: gemm (blocks [0, GEMM_BLOCKS)) || rank (blocks after).
//
// gemm is MLP-bound, not BW-bound (r10 counters: FETCH 53.7 MB < X's 102 MB ->
// X is L3-served; 2-deep reg prefetch = ~2 loads/lane in flight = the measured
// ~1 TB/s). Fix: global_load_lds staging — 8 fire-and-forget dwordx4 per thread
// per half-tile, ZERO VGPR per outstanding load (4x deeper pipeline).
// LDS: 32 KB half-tile [64 rows][128 f32]. Each wave stages exactly its own 16
// rows (instruction j covers 2 half-rows: lanes 0-31 row r0, lanes 32-63 r0+1;
// LDS dest is wave-uniform base + lane*16 as HW requires). Bank-spread via
// per-row XOR swizzle applied on the GLOBAL SOURCE col and the LDS READ col
// (identical involution, linear LDS dest — rule #21). Tail rows clamp the
// source row (no OOB; results discarded by the guarded store).
// D layout: col = t*16 + (lane&15), row = quad*4 + reg  [m89 layout]
// H stored PACKED: u32 word j = (bf16 col j) | (bf16 col j+64)<<16.
//
// rank: XCD-local L2-resident atomics; rank stores (xcc<<8)|local_rank.
__global__ __launch_bounds__(256) void gemm_rank_kernel(
    const float* __restrict__ X, const short* __restrict__ Wb,
    const float* __restrict__ bias, unsigned* __restrict__ H2,
    const int* __restrict__ rows, unsigned* __restrict__ counts,
    unsigned short* __restrict__ rank) {
  __shared__ float As[64 * 128];  // 32 KB half-tile
  if (blockIdx.x >= GEMM_BLOCKS) {
    // ---- rank path: exact partition, thread owns edges [4i, 4i+4) ----
    unsigned xcc;
    asm("s_getreg_b32 %0, hwreg(HW_REG_XCC_ID)" : "=s"(xcc));
    xcc &= 7u;
    unsigned* cbase = counts + (size_t)xcc * NNODES;
    const int e0 = ((blockIdx.x - GEMM_BLOCKS) * 256 + threadIdx.x) * 4;
    if (e0 < NEDGES) {
      const int4 r4 = *(const int4*)(rows + e0);
      const unsigned o0 = __hip_atomic_fetch_add(&cbase[r4.x], 1u, __ATOMIC_RELAXED,
                                                 __HIP_MEMORY_SCOPE_WORKGROUP);
      const unsigned o1 = __hip_atomic_fetch_add(&cbase[r4.y], 1u, __ATOMIC_RELAXED,
                                                 __HIP_MEMORY_SCOPE_WORKGROUP);
      const unsigned o2 = __hip_atomic_fetch_add(&cbase[r4.z], 1u, __ATOMIC_RELAXED,
                                                 __HIP_MEMORY_SCOPE_WORKGROUP);
      const unsigned o3 = __hip_atomic_fetch_add(&cbase[r4.w], 1u, __ATOMIC_RELAXED,
                                                 __HIP_MEMORY_SCOPE_WORKGROUP);
      ushort4 rk;
      rk.x = (unsigned short)((xcc << 8) | o0);
      rk.y = (unsigned short)((xcc << 8) | o1);
      rk.z = (unsigned short)((xcc << 8) | o2);
      rk.w = (unsigned short)((xcc << 8) | o3);
      *(ushort4*)(rank + e0) = rk;   // 8 B aligned (e0 % 4 == 0)
    }
    return;
  }
  // ---- gemm path ----
  const int lane = threadIdx.x & 63;
  const int wave = threadIdx.x >> 6;
  const int l16 = lane & 15;
  const int quad = lane >> 4;
  const int bRow0 = blockIdx.x * 64;
  const int rowBase = bRow0 + wave * 16;
  const int rl = wave * 16 + l16;           // this lane's LDS row
  const int sw = (l16 & 7) * 4;             // read-side swizzle (f32 units); rl&7 == l16&7

  floatx4 acc[8];
#pragma unroll
  for (int t = 0; t < 8; t++) acc[t] = (floatx4){0.f, 0.f, 0.f, 0.f};

#pragma unroll
  for (int h = 0; h < 2; h++) {
    // stage half h: 8 async dwordx4 per thread, no VGPR round-trip
#pragma unroll
    for (int j = 0; j < 8; j++) {
      const int r0 = wave * 16 + j * 2;            // wave-uniform
      const int rlane = r0 + (lane >> 5);          // lanes 0-31 -> r0, 32-63 -> r0+1
      int grow = bRow0 + rlane;
      if (grow >= NNODES) grow = NNODES - 1;       // tail clamp (results discarded)
      const int csrc = (((lane & 31) * 4) ^ ((rlane & 7) * 4));  // source-permuted col
      const float* src = X + (size_t)grow * KDIM + h * 128 + csrc;
      __builtin_amdgcn_global_load_lds(
          (const __attribute__((address_space(1))) void*)src,
          (__attribute__((address_space(3))) void*)(&As[r0 * 128]),
          16, 0, 0);
    }
    __syncthreads();   // barrier drain: vmcnt(0) -> staging visible
#pragma unroll
    for (int k0i = 0; k0i < 4; k0i++) {
      const int k0 = h * 4 + k0i;
      const int c = k0i * 32 + quad * 8;           // logical col within half
      const float4 c0 = *(const float4*)&As[rl * 128 + (c ^ sw)];
      const float4 c1 = *(const float4*)&As[rl * 128 + ((c + 4) ^ sw)];
      short8 a;
      a[0] = f2bf(c0.x); a[1] = f2bf(c0.y); a[2] = f2bf(c0.z); a[3] = f2bf(c0.w);
      a[4] = f2bf(c1.x); a[5] = f2bf(c1.y); a[6] = f2bf(c1.z); a[7] = f2bf(c1.w);
      const short* bp = Wb + k0 * 32 + quad * 8;
#pragma unroll
      for (int t = 0; t < 8; t++) {
        short8 b = *(const short8*)(bp + (size_t)(t * 16 + l16) * KDIM);
        acc[t] = __builtin_amdgcn_mfma_f32_16x16x32_bf16(a, b, acc[t], 0, 0, 0);
      }
    }
    if (h == 0) __syncthreads();  // all waves done reading before restage
  }

#pragma unroll
  for (int t = 0; t < 4; t++) {
    const int cl = t * 16 + l16;
    const float blo = bias[cl];
    const float bhi = bias[cl + 64];
#pragma unroll
    for (int r = 0; r < 4; r++) {
      const int row = rowBase + quad * 4 + r;
      if (row < NNODES) {
        unsigned lo = (unsigned short)f2bf(acc[t][r] + blo);
        unsigned hi = (unsigned short)f2bf(acc[t + 4][r] + bhi);
        H2[(size_t)row * 64 + cl] = lo | (hi << 16);
      }
    }
  }
}

// K2: scan1. Per node sum the 8 per-XCD counts, pad to multiple of 4,
// block-level exclusive scan -> chunkExcl + blockSums.
__global__ __launch_bounds__(256) void scan1_kernel(
    const unsigned* __restrict__ counts, int* __restrict__ chunkExcl,
    int* __restrict__ blockSums) {
  __shared__ int s[256];
  int t = threadIdx.x;
  int n = blockIdx.x * 256 + t;
  int sum = 0;
  if (n < NNODES) {
    int s0 = 0;
#pragma unroll
    for (int x = 0; x < NXCD; x++) s0 += (int)counts[(size_t)x * NNODES + n];
    sum = (s0 + 3) & ~3;  // pad segment to multiple of 4 records
  }
  s[t] = sum;
  __syncthreads();
  for (int o = 1; o < 256; o <<= 1) {
    int add = (t >= o) ? s[t - o] : 0;
    __syncthreads();
    s[t] += add;
    __syncthreads();
  }
  if (n < NNODES) chunkExcl[n] = s[t] - sum;
  if (t == 255) blockSums[blockIdx.x] = s[255];
}

// K3: merged scan2+scan3+pad-write (391 blocks x 512). Each block redundantly
// scans the 391 blockSums in LDS for its base; per node writes offsets[n],
// converts the 8 per-XCD counts into absolute base positions, zeroes the <=3
// pad records (replaces the edges memset).
__global__ __launch_bounds__(512) void scan23_kernel(
    const int* __restrict__ blockSums, const int* __restrict__ chunkExcl,
    unsigned* __restrict__ counts, int* __restrict__ offsets,
    int2* __restrict__ edges) {
  __shared__ int s[512];
  const int t = threadIdx.x;
  s[t] = (t < NB_SCAN) ? blockSums[t] : 0;
  __syncthreads();
  for (int o = 1; o < 512; o <<= 1) {
    int add = (t >= o) ? s[t - o] : 0;
    __syncthreads();
    s[t] += add;
    __syncthreads();
  }
  const int myBase = (blockIdx.x == 0) ? 0 : s[blockIdx.x - 1];
  if (blockIdx.x == 0 && t == 0) offsets[NNODES] = s[NB_SCAN - 1];
  if (t < 256) {
    const int n = blockIdx.x * 256 + t;
    if (n < NNODES) {
      const int run = chunkExcl[n] + myBase;   // multiple of 4
      offsets[n] = run;
      int c[NXCD];
      int deg = 0;
#pragma unroll
      for (int x = 0; x < NXCD; x++) {
        c[x] = (int)counts[(size_t)x * NNODES + n];
        deg += c[x];
      }
      int acc2 = run;
#pragma unroll
      for (int x = 0; x < NXCD; x++) {
        counts[(size_t)x * NNODES + n] = (unsigned)acc2;
        acc2 += c[x];
      }
      const int padded = (deg + 3) & ~3;
      const int2 zrec = {0, 0};
      for (int p = run + deg; p < run + padded; p++) edges[p] = zrec;  // pad = {col 0, val 0}
    }
  }
}

// K4: atomic-free placement: pos = xcdBase[xcc_at_rank_time][row] + local_rank.
__global__ __launch_bounds__(256) void place_kernel(
    const int* __restrict__ rows, const int* __restrict__ cols,
    const float* __restrict__ vals, const unsigned short* __restrict__ rank,
    const unsigned* __restrict__ sbase, int2* __restrict__ edges) {
  const int e0 = (blockIdx.x * 256 + threadIdx.x) * 4;
  if (e0 < NEDGES) {
    const int4 r4 = *(const int4*)(rows + e0);
    const int4 c4 = *(const int4*)(cols + e0);
    const float4 v4 = *(const float4*)(vals + e0);
    const ushort4 k4 = *(const ushort4*)(rank + e0);
    int2 rec;
    rec.x = c4.x; rec.y = __float_as_int(v4.x);
    edges[(int)sbase[(size_t)(k4.x >> 8) * NNODES + r4.x] + (int)(k4.x & 255u)] = rec;
    rec.x = c4.y; rec.y = __float_as_int(v4.y);
    edges[(int)sbase[(size_t)(k4.y >> 8) * NNODES + r4.y] + (int)(k4.y & 255u)] = rec;
    rec.x = c4.z; rec.y = __float_as_int(v4.z);
    edges[(int)sbase[(size_t)(k4.z >> 8) * NNODES + r4.z] + (int)(k4.z & 255u)] = rec;
    rec.x = c4.w; rec.y = __float_as_int(v4.w);
    edges[(int)sbase[(size_t)(k4.w >> 8) * NNODES + r4.w] + (int)(k4.w & 255u)] = rec;
  }
}

// K5: one wave per output row; lane owns channels {lane, lane+64}. Unrolled to
// 8 edges/iter (8 H-gathers in flight, 2x the MLP); segments are multiples of
// 4 -> remainder after the 8-loop is exactly 0 or 4 (single clean tail).
__global__ __launch_bounds__(256) void spmm_kernel(const int* __restrict__ offsets,
                                                   const int2* __restrict__ edges,
                                                   const unsigned* __restrict__ H2,
                                                   float* __restrict__ out) {
  const int lane = threadIdx.x & 63;
  const int row = blockIdx.x * 4 + (threadIdx.x >> 6);
  if (row >= NNODES) return;
  const int s = offsets[row];      // multiple of 4
  const int e = offsets[row + 1];
  float ax = 0.f, ay = 0.f;
  int i = s;
  for (; i + 8 <= e; i += 8) {
    const int4 p01 = *(const int4*)(edges + i);
    const int4 p23 = *(const int4*)(edges + i + 2);
    const int4 p45 = *(const int4*)(edges + i + 4);
    const int4 p67 = *(const int4*)(edges + i + 6);
    const unsigned h0 = H2[(size_t)p01.x * 64 + lane];
    const unsigned h1 = H2[(size_t)p01.z * 64 + lane];
    const unsigned h2 = H2[(size_t)p23.x * 64 + lane];
    const unsigned h3 = H2[(size_t)p23.z * 64 + lane];
    const unsigned h4 = H2[(size_t)p45.x * 64 + lane];
    const unsigned h5 = H2[(size_t)p45.z * 64 + lane];
    const unsigned h6 = H2[(size_t)p67.x * 64 + lane];
    const unsigned h7 = H2[(size_t)p67.z * 64 + lane];
    const float v0 = __int_as_float(p01.y), v1 = __int_as_float(p01.w);
    const float v2 = __int_as_float(p23.y), v3 = __int_as_float(p23.w);
    const float v4 = __int_as_float(p45.y), v5 = __int_as_float(p45.w);
    const float v6 = __int_as_float(p67.y), v7 = __int_as_float(p67.w);
    ax += v0 * __uint_as_float(h0 << 16);
    ay += v0 * __uint_as_float(h0 & 0xffff0000u);
    ax += v1 * __uint_as_float(h1 << 16);
    ay += v1 * __uint_as_float(h1 & 0xffff0000u);
    ax += v2 * __uint_as_float(h2 << 16);
    ay += v2 * __uint_as_float(h2 & 0xffff0000u);
    ax += v3 * __uint_as_float(h3 << 16);
    ay += v3 * __uint_as_float(h3 & 0xffff0000u);
    ax += v4 * __uint_as_float(h4 << 16);
    ay += v4 * __uint_as_float(h4 & 0xffff0000u);
    ax += v5 * __uint_as_float(h5 << 16);
    ay += v5 * __uint_as_float(h5 & 0xffff0000u);
    ax += v6 * __uint_as_float(h6 << 16);
    ay += v6 * __uint_as_float(h6 & 0xffff0000u);
    ax += v7 * __uint_as_float(h7 << 16);
    ay += v7 * __uint_as_float(h7 & 0xffff0000u);
  }
  if (i < e) {  // exactly 4 records remain
    const int4 p01 = *(const int4*)(edges + i);
    const int4 p23 = *(const int4*)(edges + i + 2);
    const unsigned h0 = H2[(size_t)p01.x * 64 + lane];
    const unsigned h1 = H2[(size_t)p01.z * 64 + lane];
    const unsigned h2 = H2[(size_t)p23.x * 64 + lane];
    const unsigned h3 = H2[(size_t)p23.z * 64 + lane];
    const float v0 = __int_as_float(p01.y), v1 = __int_as_float(p01.w);
    const float v2 = __int_as_float(p23.y), v3 = __int_as_float(p23.w);
    ax += v0 * __uint_as_float(h0 << 16);
    ay += v0 * __uint_as_float(h0 & 0xffff0000u);
    ax += v1 * __uint_as_float(h1 << 16);
    ay += v1 * __uint_as_float(h1 & 0xffff0000u);
    ax += v2 * __uint_as_float(h2 << 16);
    ay += v2 * __uint_as_float(h2 & 0xffff0000u);
    ax += v3 * __uint_as_float(h3 << 16);
    ay += v3 * __uint_as_float(h3 & 0xffff0000u);
  }
  out[(size_t)row * 128 + lane] = ax;
  out[(size_t)row * 128 + 64 + lane] = ay;
}

extern "C" void kernel_launch(void* const* d_in, const int* in_sizes, int n_in,
                              void* d_out, int out_size, void* d_ws, size_t ws_size,
                              hipStream_t stream) {
  const float* X = (const float*)d_in[0];
  const int* erow = (const int*)d_in[1];
  const int* ecol = (const int*)d_in[2];
  const float* eval = (const float*)d_in[3];
  const float* W = (const float*)d_in[4];
  const float* bias = (const float*)d_in[5];
  float* out = (float*)d_out;

  char* ws = (char*)d_ws;
  size_t off = 0;
  auto alloc = [&](size_t bytes) -> char* {
    char* p = ws + off;
    off += (bytes + 255) & ~(size_t)255;
    return p;
  };
  unsigned* Hb = (unsigned*)alloc((size_t)NNODES * 64 * 4);       // 25.6 MB packed
  short* Wb = (short*)alloc((size_t)ODIM * KDIM * 2);             // 64 KB
  unsigned* counts = (unsigned*)alloc((size_t)NXCD * NNODES * 4); // 3.2 MB (-> bases)
  int* chunkExcl = (int*)alloc((size_t)NNODES * 4);
  int* offsets = (int*)alloc((size_t)(NNODES + 1) * 4);
  int* blockSums = (int*)alloc((size_t)NB_SCAN * 4);
  unsigned short* rank = (unsigned short*)alloc((size_t)NEDGES * 2);  // 3.2 MB
  int2* edges = (int2*)alloc((size_t)EDGE_CAP * 8);  // 15.2 MB, padded CSR records

  init_kernel<<<CONV_BLOCKS + ZERO_BLOCKS, 256, 0, stream>>>(W, Wb, counts);
  gemm_rank_kernel<<<GEMM_BLOCKS + EDGE_BLOCKS, 256, 0, stream>>>(X, Wb, bias, Hb,
                                                                  erow, counts, rank);
  scan1_kernel<<<NB_SCAN, 256, 0, stream>>>(counts, chunkExcl, blockSums);
  scan23_kernel<<<NB_SCAN, 512, 0, stream>>>(blockSums, chunkExcl, counts, offsets, edges);
  place_kernel<<<EDGE_BLOCKS, 256, 0, stream>>>(erow, ecol, eval, rank, counts, edges);
  spmm_kernel<<<(NNODES + 3) / 4, 256, 0, stream>>>(offsets, edges, (const unsigned*)Hb, out);
}